// Round 1
// baseline (633.262 us; speedup 1.0000x reference)
//
#include <hip/hip_runtime.h>
#include <math.h>

// Problem dims
#define BT 64       // B*N sequences
#define T 256
#define DM 128      // d_model
#define DI 256      // d_inner
#define DS 16       // d_state
#define DR 8        // dt_rank
#define M_ROWS (BT*T)   // 16384

// ---------------- generic fp32 tiled GEMM: C[M,N] = A[M,K] @ W[K,N] ----------------
#define GBM 64
#define GBN 64
#define GBK 32

__global__ __launch_bounds__(256) void gemm_f32(
    const float* __restrict__ A, const float* __restrict__ W,
    float* __restrict__ C, int M, int N, int K) {
  __shared__ float sA[GBK][GBM + 4];   // sA[k][row]
  __shared__ float sB[GBK][GBN];       // sB[k][col]
  const int bm0 = blockIdx.x * GBM;
  const int bn0 = blockIdx.y * GBN;
  const int tid = threadIdx.x;
  const int tx = tid & 15;        // 0..15 -> 4 cols each
  const int ty = tid >> 4;        // 0..15 -> 4 rows each

  float acc[4][4] = {};

  for (int k0 = 0; k0 < K; k0 += GBK) {
    // load A tile 64x32 (vector loads, transposed store into sA[k][r])
#pragma unroll
    for (int i = 0; i < 2; i++) {
      int f = tid + i * 256;           // float4 index, 0..511
      int r = f >> 3;                  // row 0..63
      int c4 = f & 7;                  // 0..7
      const float4 v = *reinterpret_cast<const float4*>(&A[(size_t)(bm0 + r) * K + k0 + c4 * 4]);
      sA[c4 * 4 + 0][r] = v.x;
      sA[c4 * 4 + 1][r] = v.y;
      sA[c4 * 4 + 2][r] = v.z;
      sA[c4 * 4 + 3][r] = v.w;
    }
    // load B tile 32x64
#pragma unroll
    for (int i = 0; i < 2; i++) {
      int f = tid + i * 256;           // 0..511
      int kr = f >> 4;                 // 0..31
      int c4 = f & 15;                 // 0..15
      *reinterpret_cast<float4*>(&sB[kr][c4 * 4]) =
          *reinterpret_cast<const float4*>(&W[(size_t)(k0 + kr) * N + bn0 + c4 * 4]);
    }
    __syncthreads();

#pragma unroll
    for (int k = 0; k < GBK; k++) {
      const float4 av = *reinterpret_cast<const float4*>(&sA[k][ty * 4]);
      const float4 bv = *reinterpret_cast<const float4*>(&sB[k][tx * 4]);
      float a[4] = {av.x, av.y, av.z, av.w};
      float b[4] = {bv.x, bv.y, bv.z, bv.w};
#pragma unroll
      for (int i = 0; i < 4; i++)
#pragma unroll
        for (int j = 0; j < 4; j++)
          acc[i][j] += a[i] * b[j];
    }
    __syncthreads();
  }

#pragma unroll
  for (int i = 0; i < 4; i++) {
    float4 v = {acc[i][0], acc[i][1], acc[i][2], acc[i][3]};
    *reinterpret_cast<float4*>(&C[(size_t)(bm0 + ty * 4 + i) * N + bn0 + tx * 4]) = v;
  }
}

// ---------------- depthwise causal conv (4-tap) + bias + silu ----------------
// xz: [M_ROWS, 512]; u_pre = xz[:, 0:256]. out u: [M_ROWS, 256]
__global__ __launch_bounds__(256) void conv_silu_kernel(
    const float* __restrict__ xz, const float* __restrict__ cw,
    const float* __restrict__ cb, float* __restrict__ u) {
  const int m = blockIdx.x;          // (bt*T + t)
  const int d = threadIdx.x;         // 0..255
  const int t = m & (T - 1);
  float acc = cb[d];
#pragma unroll
  for (int j = 0; j < 4; j++) {
    int tt = t - 3 + j;
    if (tt >= 0)
      acc += xz[(size_t)(m - 3 + j) * 512 + d] * cw[d * 4 + j];
  }
  float s = acc / (1.0f + expf(-acc));   // silu
  u[(size_t)m * DI + d] = s;
}

// ---------------- per-row: dbl = u_row @ xw; delta = softplus(dt@dtw + dtb); write B,C ----------------
__global__ __launch_bounds__(256) void row_kernel(
    const float* __restrict__ u, const float* __restrict__ xw,
    const float* __restrict__ dtw, const float* __restrict__ dtb,
    float* __restrict__ delta, float* __restrict__ Bb, float* __restrict__ Cb) {
  __shared__ float us[DI];
  __shared__ float part[4][64];
  __shared__ float dbl[DR + 2 * DS];   // 40
  const int m = blockIdx.x;
  const int tid = threadIdx.x;

  us[tid] = u[(size_t)m * DI + tid];
  __syncthreads();

  const int j = tid & 63;
  const int g = tid >> 6;
  if (j < 40) {
    float acc = 0.f;
    const int k0 = g * 64;
#pragma unroll
    for (int k = 0; k < 64; k++)
      acc += us[k0 + k] * xw[(k0 + k) * 40 + j];
    part[g][j] = acc;
  }
  __syncthreads();
  if (tid < 40)
    dbl[tid] = part[0][tid] + part[1][tid] + part[2][tid] + part[3][tid];
  __syncthreads();

  // delta = softplus(dt @ dtw + dtb), dt = dbl[0:8]
  float acc = dtb[tid];
#pragma unroll
  for (int r = 0; r < DR; r++)
    acc += dbl[r] * dtw[r * DI + tid];
  // stable softplus
  float sp = fmaxf(acc, 0.0f) + log1pf(expf(-fabsf(acc)));
  delta[(size_t)m * DI + tid] = sp;

  if (tid >= DR && tid < DR + DS)
    Bb[(size_t)m * DS + (tid - DR)] = dbl[tid];
  else if (tid >= DR + DS && tid < DR + 2 * DS)
    Cb[(size_t)m * DS + (tid - DR - DS)] = dbl[tid];
}

// ---------------- selective scan + D skip + output gate ----------------
// thread layout: n = tid&15 (state), dloc = tid>>4; d = chunk*16+dloc
// grid: 64 bt * 16 chunks
__global__ __launch_bounds__(256) void scan_kernel(
    const float* __restrict__ delta, const float* __restrict__ u,
    const float* __restrict__ Bb, const float* __restrict__ Cb,
    const float* __restrict__ xz,            // for res = xz[:, 256:512]
    const float* __restrict__ A_log, const float* __restrict__ Dp,
    float* __restrict__ g) {
  const int bt = blockIdx.x >> 4;
  const int chunk = blockIdx.x & 15;
  const int tid = threadIdx.x;
  const int n = tid & 15;
  const int dloc = tid >> 4;
  const int d = chunk * 16 + dloc;

  const float An = -expf(A_log[d * DS + n]);
  const float Dpd = Dp[d];
  float h = 0.f;

  const size_t mbase = (size_t)bt * T;
  for (int t = 0; t < T; t++) {
    const size_t m = mbase + t;
    const float dl = delta[m * DI + d];
    const float uu = u[m * DI + d];
    const float Bv = Bb[m * DS + n];
    const float Cv = Cb[m * DS + n];
    const float dA = expf(dl * An);
    h = dA * h + (dl * uu) * Bv;
    float p = h * Cv;
    p += __shfl_xor(p, 8);
    p += __shfl_xor(p, 4);
    p += __shfl_xor(p, 2);
    p += __shfl_xor(p, 1);
    if (n == 0) {
      const float y = p + uu * Dpd;
      const float r = xz[m * 512 + 256 + d];
      const float sil = r / (1.0f + expf(-r));
      g[m * DI + d] = y * sil;   // aliases delta buffer (safe: read-before-write per thread)
    }
  }
}

// ---------------- launch ----------------
extern "C" void kernel_launch(void* const* d_in, const int* in_sizes, int n_in,
                              void* d_out, int out_size, void* d_ws, size_t ws_size,
                              hipStream_t stream) {
  const float* x      = (const float*)d_in[0];
  const float* in_w   = (const float*)d_in[1];   // [2,128,512]
  const float* conv_w = (const float*)d_in[2];   // [2,256,1,4]
  const float* conv_b = (const float*)d_in[3];   // [2,256]
  const float* xw     = (const float*)d_in[4];   // [2,256,40]
  const float* dtw    = (const float*)d_in[5];   // [2,8,256]
  const float* dtb    = (const float*)d_in[6];   // [2,256]
  const float* A_log  = (const float*)d_in[7];   // [2,256,16]
  const float* Dp     = (const float*)d_in[8];   // [2,256]
  const float* ow     = (const float*)d_in[9];   // [2,256,128]
  float* out = (float*)d_out;
  float* ws  = (float*)d_ws;

  float* xz = ws;                          // 16384*512  = 8388608
  float* u  = ws + 8388608;                // 16384*256  = 4194304
  float* dg = ws + 12582912;               // 16384*256  (delta, then g alias)
  float* Bb = ws + 16777216;               // 16384*16
  float* Cb = ws + 17039360;               // 16384*16
  float* hb = ws + 17301504;               // 16384*128

  for (int l = 0; l < 2; l++) {
    const float* Ain = (l == 0) ? x : hb;
    float* dst = (l == 1) ? out : hb;

    gemm_f32<<<dim3(M_ROWS / GBM, 512 / GBN), 256, 0, stream>>>(
        Ain, in_w + (size_t)l * DM * 2 * DI, xz, M_ROWS, 2 * DI, DM);

    conv_silu_kernel<<<M_ROWS, 256, 0, stream>>>(
        xz, conv_w + (size_t)l * DI * 4, conv_b + (size_t)l * DI, u);

    row_kernel<<<M_ROWS, 256, 0, stream>>>(
        u, xw + (size_t)l * DI * 40, dtw + (size_t)l * DR * DI,
        dtb + (size_t)l * DI, dg, Bb, Cb);

    scan_kernel<<<BT * 16, 256, 0, stream>>>(
        dg, u, Bb, Cb, xz, A_log + (size_t)l * DI * DS, Dp + (size_t)l * DI, dg);

    gemm_f32<<<dim3(M_ROWS / GBM, DM / GBN), 256, 0, stream>>>(
        dg, ow + (size_t)l * DI * DM, dst, M_ROWS, DM, DI);
  }
}

// Round 2
// 520.171 us; speedup vs baseline: 1.2174x; 1.2174x over previous
//
#include <hip/hip_runtime.h>
#include <math.h>

// Problem dims
#define BT 64       // B*N sequences
#define T 256
#define DM 128      // d_model
#define DI 256      // d_inner
#define DS 16       // d_state
#define DR 8        // dt_rank
#define M_ROWS (BT*T)   // 16384
#define NC 8        // time chunks for parallel scan
#define CL (T/NC)   // chunk length = 32
#define SSZ (BT*DI*DS)  // per-chunk state slab = 262144

// ---------------- generic fp32 tiled GEMM: C[M,N] = A[M,K] @ W[K,N] ----------------
#define GBM 64
#define GBN 64
#define GBK 32

__global__ __launch_bounds__(256) void gemm_f32(
    const float* __restrict__ A, const float* __restrict__ W,
    float* __restrict__ C, int M, int N, int K) {
  __shared__ float sA[GBK][GBM + 4];   // sA[k][row]
  __shared__ float sB[GBK][GBN];       // sB[k][col]
  const int bm0 = blockIdx.x * GBM;
  const int bn0 = blockIdx.y * GBN;
  const int tid = threadIdx.x;
  const int tx = tid & 15;        // 0..15 -> 4 cols each
  const int ty = tid >> 4;        // 0..15 -> 4 rows each

  float acc[4][4] = {};

  for (int k0 = 0; k0 < K; k0 += GBK) {
#pragma unroll
    for (int i = 0; i < 2; i++) {
      int f = tid + i * 256;           // float4 index, 0..511
      int r = f >> 3;                  // row 0..63
      int c4 = f & 7;                  // 0..7
      const float4 v = *reinterpret_cast<const float4*>(&A[(size_t)(bm0 + r) * K + k0 + c4 * 4]);
      sA[c4 * 4 + 0][r] = v.x;
      sA[c4 * 4 + 1][r] = v.y;
      sA[c4 * 4 + 2][r] = v.z;
      sA[c4 * 4 + 3][r] = v.w;
    }
#pragma unroll
    for (int i = 0; i < 2; i++) {
      int f = tid + i * 256;           // 0..511
      int kr = f >> 4;                 // 0..31
      int c4 = f & 15;                 // 0..15
      *reinterpret_cast<float4*>(&sB[kr][c4 * 4]) =
          *reinterpret_cast<const float4*>(&W[(size_t)(k0 + kr) * N + bn0 + c4 * 4]);
    }
    __syncthreads();

#pragma unroll
    for (int k = 0; k < GBK; k++) {
      const float4 av = *reinterpret_cast<const float4*>(&sA[k][ty * 4]);
      const float4 bv = *reinterpret_cast<const float4*>(&sB[k][tx * 4]);
      float a[4] = {av.x, av.y, av.z, av.w};
      float b[4] = {bv.x, bv.y, bv.z, bv.w};
#pragma unroll
      for (int i = 0; i < 4; i++)
#pragma unroll
        for (int j = 0; j < 4; j++)
          acc[i][j] += a[i] * b[j];
    }
    __syncthreads();
  }

#pragma unroll
  for (int i = 0; i < 4; i++) {
    float4 v = {acc[i][0], acc[i][1], acc[i][2], acc[i][3]};
    *reinterpret_cast<float4*>(&C[(size_t)(bm0 + ty * 4 + i) * N + bn0 + tx * 4]) = v;
  }
}

// ---------------- depthwise causal conv (4-tap) + bias + silu ----------------
__global__ __launch_bounds__(256) void conv_silu_kernel(
    const float* __restrict__ xz, const float* __restrict__ cw,
    const float* __restrict__ cb, float* __restrict__ u) {
  const int m = blockIdx.x;          // (bt*T + t)
  const int d = threadIdx.x;         // 0..255
  const int t = m & (T - 1);
  float acc = cb[d];
#pragma unroll
  for (int j = 0; j < 4; j++) {
    int tt = t - 3 + j;
    if (tt >= 0)
      acc += xz[(size_t)(m - 3 + j) * 512 + d] * cw[d * 4 + j];
  }
  float s = acc / (1.0f + expf(-acc));   // silu
  u[(size_t)m * DI + d] = s;
}

// ---------------- per-row: dbl = u_row @ xw; delta = softplus(dt@dtw + dtb); write B,C ----------------
__global__ __launch_bounds__(256) void row_kernel(
    const float* __restrict__ u, const float* __restrict__ xw,
    const float* __restrict__ dtw, const float* __restrict__ dtb,
    float* __restrict__ delta, float* __restrict__ Bb, float* __restrict__ Cb) {
  __shared__ float us[DI];
  __shared__ float part[4][64];
  __shared__ float dbl[DR + 2 * DS];   // 40
  const int m = blockIdx.x;
  const int tid = threadIdx.x;

  us[tid] = u[(size_t)m * DI + tid];
  __syncthreads();

  const int j = tid & 63;
  const int g = tid >> 6;
  if (j < 40) {
    float acc = 0.f;
    const int k0 = g * 64;
#pragma unroll
    for (int k = 0; k < 64; k++)
      acc += us[k0 + k] * xw[(k0 + k) * 40 + j];
    part[g][j] = acc;
  }
  __syncthreads();
  if (tid < 40)
    dbl[tid] = part[0][tid] + part[1][tid] + part[2][tid] + part[3][tid];
  __syncthreads();

  float acc = dtb[tid];
#pragma unroll
  for (int r = 0; r < DR; r++)
    acc += dbl[r] * dtw[r * DI + tid];
  float sp = fmaxf(acc, 0.0f) + log1pf(expf(-fabsf(acc)));
  delta[(size_t)m * DI + tid] = sp;

  if (tid >= DR && tid < DR + DS)
    Bb[(size_t)m * DS + (tid - DR)] = dbl[tid];
  else if (tid >= DR + DS && tid < DR + 2 * DS)
    Cb[(size_t)m * DS + (tid - DR - DS)] = dbl[tid];
}

// ---------------- chunked parallel scan ----------------
// phase1: per (bt, chunk, d, n): scan chunk from h=0; store P=prod(dA), H=chunk result
// layout: P/H[(c*BT + bt)*4096 + d*16 + n]
__global__ __launch_bounds__(256) void scan_phase1(
    const float* __restrict__ delta, const float* __restrict__ u,
    const float* __restrict__ Bb, const float* __restrict__ A_log,
    float* __restrict__ P, float* __restrict__ H) {
  const int dg = blockIdx.x;     // 0..15
  const int c  = blockIdx.y;     // 0..NC-1
  const int bt = blockIdx.z;     // 0..63
  const int tid = threadIdx.x;
  const int n = tid & 15;
  const int d = dg * 16 + (tid >> 4);

  const float An = -expf(A_log[d * DS + n]);
  float h = 0.f, p = 1.f;

  size_t m = (size_t)bt * T + c * CL;
  size_t offD = m * DI + d;
  size_t offS = m * DS + n;
#pragma unroll 4
  for (int t = 0; t < CL; t++) {
    const float dl = delta[offD];
    const float uu = u[offD];
    const float Bv = Bb[offS];
    const float dA = expf(dl * An);
    p *= dA;
    h = dA * h + (dl * uu) * Bv;
    offD += DI;
    offS += DS;
  }
  const size_t idx = ((size_t)c * BT + bt) * 4096 + (size_t)d * 16 + n;
  P[idx] = p;
  H[idx] = h;
}

// phase2: serial combine over chunks; rewrites H[c] in-place to the TRUE h at chunk entry
__global__ __launch_bounds__(256) void scan_phase2(
    const float* __restrict__ P, float* __restrict__ H) {
  const size_t i = (size_t)blockIdx.x * 256 + threadIdx.x;   // 0..SSZ-1
  float hin = 0.f;
#pragma unroll
  for (int c = 0; c < NC; c++) {
    const size_t idx = (size_t)c * SSZ + i;
    const float Pv = P[idx];
    const float Hv = H[idx];
    H[idx] = hin;                      // h at entry of chunk c
    hin = Pv * hin + Hv;
  }
}

// phase3: rescan chunk from true h0; emit y = sum_n h*C + u*D, gated by silu(res)
__global__ __launch_bounds__(256) void scan_phase3(
    const float* __restrict__ delta, const float* __restrict__ u,
    const float* __restrict__ Bb, const float* __restrict__ Cb,
    const float* __restrict__ xz, const float* __restrict__ A_log,
    const float* __restrict__ Dp, const float* __restrict__ H,
    float* __restrict__ g) {
  const int dg = blockIdx.x;
  const int c  = blockIdx.y;
  const int bt = blockIdx.z;
  const int tid = threadIdx.x;
  const int n = tid & 15;
  const int d = dg * 16 + (tid >> 4);

  const float An = -expf(A_log[d * DS + n]);
  const float Dpd = Dp[d];
  float h = H[((size_t)c * BT + bt) * 4096 + (size_t)d * 16 + n];

  size_t m = (size_t)bt * T + c * CL;
  size_t offD = m * DI + d;
  size_t offS = m * DS + n;
  for (int t = 0; t < CL; t++) {
    const float dl = delta[offD];
    const float uu = u[offD];
    const float Bv = Bb[offS];
    const float Cv = Cb[offS];
    const float dA = expf(dl * An);
    h = dA * h + (dl * uu) * Bv;
    float pr = h * Cv;
    pr += __shfl_xor(pr, 8);
    pr += __shfl_xor(pr, 4);
    pr += __shfl_xor(pr, 2);
    pr += __shfl_xor(pr, 1);
    if (n == 0) {
      const float y = pr + uu * Dpd;
      const float r = xz[(m + t) * 512 + 256 + d];
      const float sil = r / (1.0f + expf(-r));
      g[offD] = y * sil;   // aliases delta (read-before-write within wave, per-t disjoint across chunks)
    }
    offD += DI;
    offS += DS;
  }
}

// ---------------- launch ----------------
extern "C" void kernel_launch(void* const* d_in, const int* in_sizes, int n_in,
                              void* d_out, int out_size, void* d_ws, size_t ws_size,
                              hipStream_t stream) {
  const float* x      = (const float*)d_in[0];
  const float* in_w   = (const float*)d_in[1];   // [2,128,512]
  const float* conv_w = (const float*)d_in[2];   // [2,256,1,4]
  const float* conv_b = (const float*)d_in[3];   // [2,256]
  const float* xw     = (const float*)d_in[4];   // [2,256,40]
  const float* dtw    = (const float*)d_in[5];   // [2,8,256]
  const float* dtb    = (const float*)d_in[6];   // [2,256]
  const float* A_log  = (const float*)d_in[7];   // [2,256,16]
  const float* Dp     = (const float*)d_in[8];   // [2,256]
  const float* ow     = (const float*)d_in[9];   // [2,256,128]
  float* out = (float*)d_out;
  float* ws  = (float*)d_ws;

  float* xz = ws;                          // 16384*512  = 8388608
  float* u  = ws + 8388608;                // 16384*256
  float* dg = ws + 12582912;               // 16384*256  (delta, then g alias)
  float* Bb = ws + 16777216;               // 16384*16
  float* Cb = ws + 17039360;               // 16384*16
  float* hb = ws + 17301504;               // 16384*128
  float* Pb = ws + 19398656;               // NC*SSZ = 2097152
  float* Hb = ws + 21495808;               // NC*SSZ = 2097152   (end: 23592960 floats = 94.4 MB)

  for (int l = 0; l < 2; l++) {
    const float* Ain = (l == 0) ? x : hb;
    float* dst = (l == 1) ? out : hb;

    gemm_f32<<<dim3(M_ROWS / GBM, 512 / GBN), 256, 0, stream>>>(
        Ain, in_w + (size_t)l * DM * 2 * DI, xz, M_ROWS, 2 * DI, DM);

    conv_silu_kernel<<<M_ROWS, 256, 0, stream>>>(
        xz, conv_w + (size_t)l * DI * 4, conv_b + (size_t)l * DI, u);

    row_kernel<<<M_ROWS, 256, 0, stream>>>(
        u, xw + (size_t)l * DI * 40, dtw + (size_t)l * DR * DI,
        dtb + (size_t)l * DI, dg, Bb, Cb);

    scan_phase1<<<dim3(16, NC, BT), 256, 0, stream>>>(
        dg, u, Bb, A_log + (size_t)l * DI * DS, Pb, Hb);

    scan_phase2<<<SSZ / 256, 256, 0, stream>>>(Pb, Hb);

    scan_phase3<<<dim3(16, NC, BT), 256, 0, stream>>>(
        dg, u, Bb, Cb, xz, A_log + (size_t)l * DI * DS, Dp + (size_t)l * DI,
        Hb, dg);

    gemm_f32<<<dim3(M_ROWS / GBM, DM / GBN), 256, 0, stream>>>(
        dg, ow + (size_t)l * DI * DM, dst, M_ROWS, DM, DI);
  }
}

// Round 3
// 325.132 us; speedup vs baseline: 1.9477x; 1.5999x over previous
//
#include <hip/hip_runtime.h>
#include <math.h>

// Problem dims
#define BT 64       // B*N sequences
#define T 256
#define DM 128      // d_model
#define DI 256      // d_inner
#define DS 16       // d_state
#define DR 8        // dt_rank
#define M_ROWS (BT*T)   // 16384
#define NC 16       // time chunks for parallel scan
#define CL (T/NC)   // chunk length = 16
#define SSZ (BT*DI*DS)  // per-chunk state slab = 262144

__device__ __forceinline__ float fast_silu(float x) {
  return x * __builtin_amdgcn_rcpf(1.0f + __expf(-x));
}
// P is stored in the dead u-pre half of xz (cols 0..255 of each 512-wide row)
__device__ __forceinline__ size_t paddr(size_t f) {
  return (f >> 8) * 512 + (f & 255);
}

// ---------------- generic fp32 tiled GEMM: C[M,N] = A[M,K] @ W[K,N] ----------------
#define GBM 64
#define GBN 64
#define GBK 32

__global__ __launch_bounds__(256) void gemm_f32(
    const float* __restrict__ A, const float* __restrict__ W,
    float* __restrict__ C, int M, int N, int K) {
  __shared__ float sA[GBK][GBM + 4];
  __shared__ float sB[GBK][GBN];
  const int bm0 = blockIdx.x * GBM;
  const int bn0 = blockIdx.y * GBN;
  const int tid = threadIdx.x;
  const int tx = tid & 15;
  const int ty = tid >> 4;

  float acc[4][4] = {};

  for (int k0 = 0; k0 < K; k0 += GBK) {
#pragma unroll
    for (int i = 0; i < 2; i++) {
      int f = tid + i * 256;
      int r = f >> 3;
      int c4 = f & 7;
      const float4 v = *reinterpret_cast<const float4*>(&A[(size_t)(bm0 + r) * K + k0 + c4 * 4]);
      sA[c4 * 4 + 0][r] = v.x;
      sA[c4 * 4 + 1][r] = v.y;
      sA[c4 * 4 + 2][r] = v.z;
      sA[c4 * 4 + 3][r] = v.w;
    }
#pragma unroll
    for (int i = 0; i < 2; i++) {
      int f = tid + i * 256;
      int kr = f >> 4;
      int c4 = f & 15;
      *reinterpret_cast<float4*>(&sB[kr][c4 * 4]) =
          *reinterpret_cast<const float4*>(&W[(size_t)(k0 + kr) * N + bn0 + c4 * 4]);
    }
    __syncthreads();

#pragma unroll
    for (int k = 0; k < GBK; k++) {
      const float4 av = *reinterpret_cast<const float4*>(&sA[k][ty * 4]);
      const float4 bv = *reinterpret_cast<const float4*>(&sB[k][tx * 4]);
      float a[4] = {av.x, av.y, av.z, av.w};
      float b[4] = {bv.x, bv.y, bv.z, bv.w};
#pragma unroll
      for (int i = 0; i < 4; i++)
#pragma unroll
        for (int j = 0; j < 4; j++)
          acc[i][j] += a[i] * b[j];
    }
    __syncthreads();
  }

#pragma unroll
  for (int i = 0; i < 4; i++) {
    float4 v = {acc[i][0], acc[i][1], acc[i][2], acc[i][3]};
    *reinterpret_cast<float4*>(&C[(size_t)(bm0 + ty * 4 + i) * N + bn0 + tx * 4]) = v;
  }
}

// ---------------- depthwise causal conv (4-tap) + bias + silu; also silu(res) in place ----------------
__global__ __launch_bounds__(256) void conv_silu_kernel(
    const float* __restrict__ xzr, float* __restrict__ xzw,
    const float* __restrict__ cw, const float* __restrict__ cb,
    float* __restrict__ u) {
  const int m = blockIdx.x;          // (bt*T + t)
  const int d = threadIdx.x;         // 0..255
  const int t = m & (T - 1);
  float acc = cb[d];
#pragma unroll
  for (int j = 0; j < 4; j++) {
    int tt = t - 3 + j;
    if (tt >= 0)
      acc += xzr[(size_t)(m - 3 + j) * 512 + d] * cw[d * 4 + j];
  }
  u[(size_t)m * DI + d] = fast_silu(acc);
  // gate: silu(res) in place (each (m,d) owned by exactly one thread)
  const size_t ra = (size_t)m * 512 + 256 + d;
  xzw[ra] = fast_silu(xzr[ra]);
}

// ---------------- per-row: dbl = u_row @ xw; delta = softplus(dt@dtw + dtb); write B,C ----------------
__global__ __launch_bounds__(256) void row_kernel(
    const float* __restrict__ u, const float* __restrict__ xw,
    const float* __restrict__ dtw, const float* __restrict__ dtb,
    float* __restrict__ delta, float* __restrict__ Bb, float* __restrict__ Cb) {
  __shared__ float us[DI];
  __shared__ float part[4][64];
  __shared__ float dbl[DR + 2 * DS];   // 40
  const int m = blockIdx.x;
  const int tid = threadIdx.x;

  us[tid] = u[(size_t)m * DI + tid];
  __syncthreads();

  const int j = tid & 63;
  const int g = tid >> 6;
  if (j < 40) {
    float acc = 0.f;
    const int k0 = g * 64;
#pragma unroll
    for (int k = 0; k < 64; k++)
      acc += us[k0 + k] * xw[(k0 + k) * 40 + j];
    part[g][j] = acc;
  }
  __syncthreads();
  if (tid < 40)
    dbl[tid] = part[0][tid] + part[1][tid] + part[2][tid] + part[3][tid];
  __syncthreads();

  float acc = dtb[tid];
#pragma unroll
  for (int r = 0; r < DR; r++)
    acc += dbl[r] * dtw[r * DI + tid];
  // stable softplus with native exp/log
  float sp = fmaxf(acc, 0.0f) + __logf(1.0f + __expf(-fabsf(acc)));
  delta[(size_t)m * DI + tid] = sp;

  if (tid >= DR && tid < DR + DS)
    Bb[(size_t)m * DS + (tid - DR)] = dbl[tid];
  else if (tid >= DR + DS && tid < DR + 2 * DS)
    Cb[(size_t)m * DS + (tid - DR - DS)] = dbl[tid];
}

// ---------------- chunked parallel scan (all 16 n-states per thread) ----------------
// phase1: per (bt,c,d): scan chunk from h=0; store H (chunk result) and P=exp(An*sum dl)
__global__ __launch_bounds__(256) void scan_phase1(
    const float* __restrict__ delta, const float* __restrict__ u,
    const float* __restrict__ Bb, const float* __restrict__ A_log,
    float* __restrict__ Pal, float* __restrict__ H) {
  const int c  = blockIdx.x;
  const int bt = blockIdx.y;
  const int d  = threadIdx.x;

  float An[16];
  const float4* al = reinterpret_cast<const float4*>(&A_log[d * DS]);
#pragma unroll
  for (int q = 0; q < 4; q++) {
    float4 a = al[q];
    An[q * 4 + 0] = -__expf(a.x);
    An[q * 4 + 1] = -__expf(a.y);
    An[q * 4 + 2] = -__expf(a.z);
    An[q * 4 + 3] = -__expf(a.w);
  }

  float h[16];
#pragma unroll
  for (int n = 0; n < 16; n++) h[n] = 0.f;
  float Sdl = 0.f;

  const size_t m0 = (size_t)bt * T + c * CL;
  for (int t = 0; t < CL; t++) {
    const size_t m = m0 + t;
    const float dl = delta[m * DI + d];
    const float uu = u[m * DI + d];
    const float du = dl * uu;
    Sdl += dl;
    const float4* bp = reinterpret_cast<const float4*>(&Bb[m * DS]);
    const float4 B0 = bp[0], B1 = bp[1], B2 = bp[2], B3 = bp[3];
    const float Bv[16] = {B0.x, B0.y, B0.z, B0.w, B1.x, B1.y, B1.z, B1.w,
                          B2.x, B2.y, B2.z, B2.w, B3.x, B3.y, B3.z, B3.w};
#pragma unroll
    for (int n = 0; n < 16; n++) {
      const float dA = __expf(dl * An[n]);
      h[n] = dA * h[n] + du * Bv[n];
    }
  }

  const size_t idx = ((size_t)c * BT + bt) * 4096 + (size_t)d * 16;
#pragma unroll
  for (int q = 0; q < 4; q++) {
    float4 hv = {h[q * 4 + 0], h[q * 4 + 1], h[q * 4 + 2], h[q * 4 + 3]};
    *reinterpret_cast<float4*>(&H[idx + q * 4]) = hv;
  }
#pragma unroll
  for (int q = 0; q < 4; q++) {
    float4 pv = {__expf(An[q * 4 + 0] * Sdl), __expf(An[q * 4 + 1] * Sdl),
                 __expf(An[q * 4 + 2] * Sdl), __expf(An[q * 4 + 3] * Sdl)};
    *reinterpret_cast<float4*>(&Pal[paddr(idx + q * 4)]) = pv;
  }
}

// phase2: serial combine over chunks; rewrites H[c] in-place to TRUE h at chunk entry
__global__ __launch_bounds__(256) void scan_phase2(
    const float* __restrict__ Pal, float* __restrict__ H) {
  const size_t i = (size_t)blockIdx.x * 256 + threadIdx.x;   // 0..SSZ-1
  float hin = 0.f;
#pragma unroll
  for (int c = 0; c < NC; c++) {
    const size_t idx = (size_t)c * SSZ + i;
    const float Pv = Pal[paddr(idx)];
    const float Hv = H[idx];
    H[idx] = hin;
    hin = Pv * hin + Hv;
  }
}

// phase3: rescan chunk from true h0; y = sum_n h*C + u*D; g = y * silu(res)
__global__ __launch_bounds__(256) void scan_phase3(
    const float* __restrict__ delta, const float* __restrict__ u,
    const float* __restrict__ Bb, const float* __restrict__ Cb,
    const float* __restrict__ xz,            // res half pre-silu'd by conv kernel
    const float* __restrict__ A_log, const float* __restrict__ Dp,
    const float* __restrict__ H, float* __restrict__ g) {
  const int c  = blockIdx.x;
  const int bt = blockIdx.y;
  const int d  = threadIdx.x;

  float An[16];
  const float4* al = reinterpret_cast<const float4*>(&A_log[d * DS]);
#pragma unroll
  for (int q = 0; q < 4; q++) {
    float4 a = al[q];
    An[q * 4 + 0] = -__expf(a.x);
    An[q * 4 + 1] = -__expf(a.y);
    An[q * 4 + 2] = -__expf(a.z);
    An[q * 4 + 3] = -__expf(a.w);
  }
  const float Dpd = Dp[d];

  float h[16];
  const size_t idx = ((size_t)c * BT + bt) * 4096 + (size_t)d * 16;
#pragma unroll
  for (int q = 0; q < 4; q++) {
    float4 hv = *reinterpret_cast<const float4*>(&H[idx + q * 4]);
    h[q * 4 + 0] = hv.x; h[q * 4 + 1] = hv.y; h[q * 4 + 2] = hv.z; h[q * 4 + 3] = hv.w;
  }

  const size_t m0 = (size_t)bt * T + c * CL;
  for (int t = 0; t < CL; t++) {
    const size_t m = m0 + t;
    const float dl = delta[m * DI + d];
    const float uu = u[m * DI + d];
    const float du = dl * uu;
    const float4* bp = reinterpret_cast<const float4*>(&Bb[m * DS]);
    const float4 B0 = bp[0], B1 = bp[1], B2 = bp[2], B3 = bp[3];
    const float4* cp = reinterpret_cast<const float4*>(&Cb[m * DS]);
    const float4 C0 = cp[0], C1 = cp[1], C2 = cp[2], C3 = cp[3];
    const float Bv[16] = {B0.x, B0.y, B0.z, B0.w, B1.x, B1.y, B1.z, B1.w,
                          B2.x, B2.y, B2.z, B2.w, B3.x, B3.y, B3.z, B3.w};
    const float Cv[16] = {C0.x, C0.y, C0.z, C0.w, C1.x, C1.y, C1.z, C1.w,
                          C2.x, C2.y, C2.z, C2.w, C3.x, C3.y, C3.z, C3.w};
    float y = 0.f;
#pragma unroll
    for (int n = 0; n < 16; n++) {
      const float dA = __expf(dl * An[n]);
      h[n] = dA * h[n] + du * Bv[n];
      y += h[n] * Cv[n];
    }
    const float rs = xz[m * 512 + 256 + d];       // already silu'd
    g[m * DI + d] = (y + uu * Dpd) * rs;          // aliases delta (same-thread RAW only)
  }
}

// ---------------- launch ----------------
extern "C" void kernel_launch(void* const* d_in, const int* in_sizes, int n_in,
                              void* d_out, int out_size, void* d_ws, size_t ws_size,
                              hipStream_t stream) {
  const float* x      = (const float*)d_in[0];
  const float* in_w   = (const float*)d_in[1];   // [2,128,512]
  const float* conv_w = (const float*)d_in[2];   // [2,256,1,4]
  const float* conv_b = (const float*)d_in[3];   // [2,256]
  const float* xw     = (const float*)d_in[4];   // [2,256,40]
  const float* dtw    = (const float*)d_in[5];   // [2,8,256]
  const float* dtb    = (const float*)d_in[6];   // [2,256]
  const float* A_log  = (const float*)d_in[7];   // [2,256,16]
  const float* Dp     = (const float*)d_in[8];   // [2,256]
  const float* ow     = (const float*)d_in[9];   // [2,256,128]
  float* out = (float*)d_out;
  float* ws  = (float*)d_ws;

  float* xz = ws;                          // 16384*512; u-pre half hosts P after conv
  float* u  = ws + 8388608;                // 16384*256
  float* dg = ws + 12582912;               // 16384*256 (delta, then g alias)
  float* Bb = ws + 16777216;               // 16384*16
  float* Cb = ws + 17039360;               // 16384*16
  float* hb = ws + 17301504;               // 16384*128
  float* Hb = ws + 19398656;               // NC*SSZ = 4194304 (end 23592960 floats = 94.4MB)

  for (int l = 0; l < 2; l++) {
    const float* Ain = (l == 0) ? x : hb;
    float* dst = (l == 1) ? out : hb;

    gemm_f32<<<dim3(M_ROWS / GBM, 512 / GBN), 256, 0, stream>>>(
        Ain, in_w + (size_t)l * DM * 2 * DI, xz, M_ROWS, 2 * DI, DM);

    conv_silu_kernel<<<M_ROWS, 256, 0, stream>>>(
        xz, xz, conv_w + (size_t)l * DI * 4, conv_b + (size_t)l * DI, u);

    row_kernel<<<M_ROWS, 256, 0, stream>>>(
        u, xw + (size_t)l * DI * 40, dtw + (size_t)l * DR * DI,
        dtb + (size_t)l * DI, dg, Bb, Cb);

    scan_phase1<<<dim3(NC, BT), 256, 0, stream>>>(
        dg, u, Bb, A_log + (size_t)l * DI * DS, xz, Hb);

    scan_phase2<<<SSZ / 256, 256, 0, stream>>>(xz, Hb);

    scan_phase3<<<dim3(NC, BT), 256, 0, stream>>>(
        dg, u, Bb, Cb, xz, A_log + (size_t)l * DI * DS, Dp + (size_t)l * DI,
        Hb, dg);

    gemm_f32<<<dim3(M_ROWS / GBM, DM / GBN), 256, 0, stream>>>(
        dg, ow + (size_t)l * DI * DM, dst, M_ROWS, DM, DI);
  }
}